// Round 5
// baseline (181.434 us; speedup 1.0000x reference)
//
#include <hip/hip_runtime.h>
#include <math.h>

#define NB 8
#define NQ 128
#define NK 1024
#define ND 512   // QK_DIM
#define NH 256   // HID
#define NV 512   // VDIM

typedef __attribute__((ext_vector_type(8))) short short8v;   // 8 bf16
typedef __attribute__((ext_vector_type(4))) float floatx4;

// ---------- bf16 helpers (RNE) ----------
__device__ __forceinline__ ushort f2bf(float f) {
  union { float f; unsigned u; } v; v.f = f;
  unsigned r = (v.u + 0x7FFF + ((v.u >> 16) & 1)) >> 16;
  return (ushort)r;
}
__device__ __forceinline__ float bf2f(ushort b) {
  union { unsigned u; float f; } v; v.u = ((unsigned)b) << 16;
  return v.f;
}
__device__ __forceinline__ float wave_rsum(float v) {
#pragma unroll
  for (int off = 32; off; off >>= 1) v += __shfl_xor(v, off);
  return v;
}

// =====================================================================
// K0a: W [ND][NH] f32 -> Wt hi/lo [NH][ND] bf16 (transposed + split).
// =====================================================================
__global__ __launch_bounds__(256) void splitw_kernel(
    const float* __restrict__ Wq, const float* __restrict__ Wk,
    ushort* __restrict__ WtQh, ushort* __restrict__ WtQl,
    ushort* __restrict__ WtKh, ushort* __restrict__ WtKl) {
  const int t = threadIdx.x;
  const int mat = blockIdx.x >> 7;
  const int bi = blockIdx.x & 127;            // 16 d-tiles x 8 h-tiles
  const int d0 = (bi >> 3) * 32, h0 = (bi & 7) * 32;
  const float* W = mat ? Wk : Wq;
  ushort* Oh = mat ? WtKh : WtQh;
  ushort* Ol = mat ? WtKl : WtQl;
  __shared__ float tile[32][33];
#pragma unroll
  for (int i = 0; i < 4; ++i) {
    int idx = t + 256 * i;
    int r = idx >> 5, c = idx & 31;
    tile[r][c] = W[(size_t)(d0 + r) * NH + h0 + c];
  }
  __syncthreads();
#pragma unroll
  for (int i = 0; i < 4; ++i) {
    int idx = t + 256 * i;
    int hh = idx >> 5, dd = idx & 31;
    float f = tile[dd][hh];
    ushort hi = f2bf(f);
    float lo = f - bf2f(hi);
    Oh[(size_t)(h0 + hh) * ND + d0 + dd] = hi;
    Ol[(size_t)(h0 + hh) * ND + d0 + dd] = f2bf(lo);
  }
}

// =====================================================================
// K0b: values [b][k][v] f32 -> VhT [b][v][k] bf16 (transpose, 32x32 tiles).
// k-tiles beyond ceil32(valid_len) are never read downstream -> skip.
// =====================================================================
__global__ __launch_bounds__(256) void convert_v_kernel(
    const float* __restrict__ values, const int* __restrict__ valid_lens,
    ushort* __restrict__ VhT) {
  const int b = blockIdx.z;
  const int k0 = blockIdx.x * 32;     // gridDim.x = 32
  const int v0 = blockIdx.y * 32;     // gridDim.y = 16
  const int V = valid_lens[b];
  if (k0 >= ((V + 31) & ~31)) return;  // uniform per block
  const int t = threadIdx.x;
  __shared__ float tile[32][33];
#pragma unroll
  for (int i = 0; i < 4; ++i) {
    int idx = t + 256 * i;
    int kk = idx >> 5, vv = idx & 31;   // coalesced along v
    tile[kk][vv] = values[(size_t)(b * NK + k0 + kk) * NV + v0 + vv];
  }
  __syncthreads();
#pragma unroll
  for (int i = 0; i < 4; ++i) {
    int idx = t + 256 * i;
    int vv = idx >> 5, kk = idx & 31;   // coalesced along k
    VhT[(size_t)(b * NV + v0 + vv) * NK + k0 + kk] = f2bf(tile[kk][vv]);
  }
}

// =====================================================================
// K1 v3: projection via split-bf16 MFMA + exp(2x) epilogue.
// Block = 256 thr (4 waves) = 16 rows x 256 cols; wave w -> cols w*64..+63
// (4 x 16x16 frags). A tile staged ONCE in LDS pre-converted to bf16
// hi/lo (padded rows 520 -> conflict-free b128 frag reads). W loads
// ping-pong register-prefetched (depth 1.5) so MFMAs hide L2 latency.
// grid 576: bx<64 q-tiles -> Eq f32; else k-tiles -> EkT bf16 (skip >= V).
// acc = Ahi*Whi + Ahi*Wlo + Alo*Whi  (~f32 precision).
// =====================================================================
__global__ __launch_bounds__(256) void proj_mfma_kernel(
    const float* __restrict__ queries, const float* __restrict__ keys,
    const ushort* __restrict__ WtQh, const ushort* __restrict__ WtQl,
    const ushort* __restrict__ WtKh, const ushort* __restrict__ WtKl,
    const int* __restrict__ valid_lens,
    float* __restrict__ Eq, ushort* __restrict__ EkTb) {
  const int t = threadIdx.x;
  const int lane = t & 63, wvid = t >> 6;
  const int lr = lane & 15, lg = lane >> 4;
  const int bx = blockIdx.x;
  const bool isQ = bx < 64;
  const float* A;
  const ushort *Wh, *Wl;
  int arow0, b = 0, rin = 0;
  if (isQ) {
    A = queries; Wh = WtQh; Wl = WtQl; arow0 = bx * 16;
  } else {
    int kt = bx - 64;                // 0..511
    b = kt >> 6; rin = (kt & 63) * 16;
    if (rin >= valid_lens[b]) return;
    A = keys; Wh = WtKh; Wl = WtKl; arow0 = b * NK + rin;
  }

  // ---- stage A tile (16x512) pre-split to bf16 hi/lo in LDS ----
  __shared__ ushort Ah[16][520];   // pad 520: frag reads spread 8 bank-groups
  __shared__ ushort Al[16][520];
  {
    const float* Arow = A + (size_t)arow0 * ND;  // 16 rows contiguous
#pragma unroll
    for (int i = 0; i < 8; ++i) {
      int e = (t + 256 * i) * 4;       // elem 0..8191
      int r = e >> 9, c = e & 511;
      float4 a = *(const float4*)&Arow[e];
      ushort4 h, l;
      h.x = f2bf(a.x); l.x = f2bf(a.x - bf2f(h.x));
      h.y = f2bf(a.y); l.y = f2bf(a.y - bf2f(h.y));
      h.z = f2bf(a.z); l.z = f2bf(a.z - bf2f(h.z));
      h.w = f2bf(a.w); l.w = f2bf(a.w - bf2f(h.w));
      *(ushort4*)&Ah[r][c] = h;
      *(ushort4*)&Al[r][c] = l;
    }
  }
  __syncthreads();

  const int c0w = wvid * 64;
  const ushort* Whb = Wh + (size_t)(c0w + lr) * ND + lg * 8;
  const ushort* Wlb = Wl + (size_t)(c0w + lr) * ND + lg * 8;

  floatx4 acc[4];
#pragma unroll
  for (int cf = 0; cf < 4; ++cf) acc[cf] = (floatx4){0.f, 0.f, 0.f, 0.f};

#define LOADW(dsth, dstl, kkv)                                            \
  {                                                                       \
    const size_t _d = (size_t)(kkv) * 32;                                 \
    dsth##0 = *(const short8v*)&Whb[_d];                                  \
    dstl##0 = *(const short8v*)&Wlb[_d];                                  \
    dsth##1 = *(const short8v*)&Whb[(size_t)16 * ND + _d];                \
    dstl##1 = *(const short8v*)&Wlb[(size_t)16 * ND + _d];                \
    dsth##2 = *(const short8v*)&Whb[(size_t)32 * ND + _d];                \
    dstl##2 = *(const short8v*)&Wlb[(size_t)32 * ND + _d];                \
    dsth##3 = *(const short8v*)&Whb[(size_t)48 * ND + _d];                \
    dstl##3 = *(const short8v*)&Wlb[(size_t)48 * ND + _d];                \
  }

#define MFMA4(ah_, al_, wh, wl)                                           \
  {                                                                       \
    acc[0] = __builtin_amdgcn_mfma_f32_16x16x32_bf16(al_, wh##0, acc[0], 0, 0, 0); \
    acc[0] = __builtin_amdgcn_mfma_f32_16x16x32_bf16(ah_, wl##0, acc[0], 0, 0, 0); \
    acc[0] = __builtin_amdgcn_mfma_f32_16x16x32_bf16(ah_, wh##0, acc[0], 0, 0, 0); \
    acc[1] = __builtin_amdgcn_mfma_f32_16x16x32_bf16(al_, wh##1, acc[1], 0, 0, 0); \
    acc[1] = __builtin_amdgcn_mfma_f32_16x16x32_bf16(ah_, wl##1, acc[1], 0, 0, 0); \
    acc[1] = __builtin_amdgcn_mfma_f32_16x16x32_bf16(ah_, wh##1, acc[1], 0, 0, 0); \
    acc[2] = __builtin_amdgcn_mfma_f32_16x16x32_bf16(al_, wh##2, acc[2], 0, 0, 0); \
    acc[2] = __builtin_amdgcn_mfma_f32_16x16x32_bf16(ah_, wl##2, acc[2], 0, 0, 0); \
    acc[2] = __builtin_amdgcn_mfma_f32_16x16x32_bf16(ah_, wh##2, acc[2], 0, 0, 0); \
    acc[3] = __builtin_amdgcn_mfma_f32_16x16x32_bf16(al_, wh##3, acc[3], 0, 0, 0); \
    acc[3] = __builtin_amdgcn_mfma_f32_16x16x32_bf16(ah_, wl##3, acc[3], 0, 0, 0); \
    acc[3] = __builtin_amdgcn_mfma_f32_16x16x32_bf16(ah_, wh##3, acc[3], 0, 0, 0); \
  }

  short8v wAh0, wAh1, wAh2, wAh3, wAl0, wAl1, wAl2, wAl3;
  short8v wBh0, wBh1, wBh2, wBh3, wBl0, wBl1, wBl2, wBl3;
  LOADW(wAh, wAl, 0);
#pragma unroll 1
  for (int kk = 0; kk < 16; kk += 2) {
    LOADW(wBh, wBl, kk + 1);
    {
      short8v ah_ = *(const short8v*)&Ah[lr][kk * 32 + lg * 8];
      short8v al_ = *(const short8v*)&Al[lr][kk * 32 + lg * 8];
      MFMA4(ah_, al_, wAh, wAl);
    }
    if (kk + 2 < 16) LOADW(wAh, wAl, kk + 2);
    {
      short8v ah_ = *(const short8v*)&Ah[lr][(kk + 1) * 32 + lg * 8];
      short8v al_ = *(const short8v*)&Al[lr][(kk + 1) * 32 + lg * 8];
      MFMA4(ah_, al_, wBh, wBl);
    }
  }
#undef LOADW
#undef MFMA4

  const float C2 = 2.885390081777927f;  // 2*log2(e)
  if (isQ) {
#pragma unroll
    for (int cf = 0; cf < 4; ++cf) {
      const int h = c0w + cf * 16 + lr;
#pragma unroll
      for (int reg = 0; reg < 4; ++reg) {
        const int row = arow0 + lg * 4 + reg;
        float p = fminf(fmaxf(acc[cf][reg], -15.f), 15.f);
        Eq[(size_t)row * NH + h] = exp2f(p * C2);
      }
    }
  } else {
#pragma unroll
    for (int cf = 0; cf < 4; ++cf) {
      const int h = c0w + cf * 16 + lr;
      ushort4 e;
      e.x = f2bf(exp2f(fminf(fmaxf(acc[cf][0], -15.f), 15.f) * C2));
      e.y = f2bf(exp2f(fminf(fmaxf(acc[cf][1], -15.f), 15.f) * C2));
      e.z = f2bf(exp2f(fminf(fmaxf(acc[cf][2], -15.f), 15.f) * C2));
      e.w = f2bf(exp2f(fminf(fmaxf(acc[cf][3], -15.f), 15.f) * C2));
      *(ushort4*)&EkTb[((size_t)(b * NH + h)) * NK + rin + lg * 4] = e;
    }
  }
}

// =====================================================================
// K2 v3: scores -> fixed-shift softmax numerators (bf16) + row sums.
// p = exp2(-2log2e*(racc+SN)), SN = sum_h max(-wv_h,0)  (exact shift).
// Inner loop: 8-h chunks; eq/wv batch-loaded to regs via float4 LDS
// reads; Ek loads ping-pong prefetched. grid (64 q-pairs, 4 kt, 8 b).
// =====================================================================
__global__ __launch_bounds__(256) void score_kernel(
    const float* __restrict__ Eq, const ushort* __restrict__ EkTb,
    const float* __restrict__ wvp, const int* __restrict__ valid_lens,
    ushort* __restrict__ Pb, float* __restrict__ rowsum) {
  const int b = blockIdx.z;
  const int V = valid_lens[b];
  const int k0 = blockIdx.y * 256;
  if (k0 >= V) return;
  const int t = threadIdx.x;
  const int q0 = blockIdx.x * 2;
  const int lane = t & 63, wid = t >> 6;
  const float L2E2 = 2.8853900817779268f;  // 2*log2(e)

  __shared__ __align__(16) float eqs[2][NH];
  __shared__ __align__(16) float wvs[NH];
  __shared__ float red[8];

  if (t < 128)
    ((float4*)eqs)[t] = ((const float4*)&Eq[(size_t)(b * NQ + q0) * NH])[t];
  wvs[t] = wvp[t];
  __syncthreads();

  float mn = wave_rsum(fminf(wvs[t], 0.f));
  if (lane == 0) red[wid] = mn;
  __syncthreads();
  const float SN = -(red[0] + red[1] + red[2] + red[3]);
  __syncthreads();

  const ushort* ek = EkTb + (size_t)b * NH * NK + k0 + t;
  float acc0 = 0.f, acc1 = 0.f;

  ushort uA[8], uB[8];
#define LOADE(u, h0)                                                      \
  {                                                                       \
    _Pragma("unroll") for (int j = 0; j < 8; ++j)                         \
        u[j] = ek[(size_t)((h0) + j) * NK];                               \
  }
#define CHUNK(u, h0)                                                      \
  {                                                                       \
    float e0[8], e1[8], w8[8];                                            \
    *(float4*)&e0[0] = *(const float4*)&eqs[0][(h0)];                     \
    *(float4*)&e0[4] = *(const float4*)&eqs[0][(h0) + 4];                 \
    *(float4*)&e1[0] = *(const float4*)&eqs[1][(h0)];                     \
    *(float4*)&e1[4] = *(const float4*)&eqs[1][(h0) + 4];                 \
    *(float4*)&w8[0] = *(const float4*)&wvs[(h0)];                        \
    *(float4*)&w8[4] = *(const float4*)&wvs[(h0) + 4];                    \
    _Pragma("unroll") for (int j = 0; j < 8; ++j) {                       \
      const float ev = bf2f(u[j]);                                        \
      acc0 += w8[j] * __builtin_amdgcn_rcpf(__builtin_fmaf(e0[j], ev, 1.f)); \
      acc1 += w8[j] * __builtin_amdgcn_rcpf(__builtin_fmaf(e1[j], ev, 1.f)); \
    }                                                                     \
  }

  LOADE(uA, 0);
#pragma unroll 1
  for (int h0 = 0; h0 < NH; h0 += 16) {
    LOADE(uB, h0 + 8);
    CHUNK(uA, h0);
    if (h0 + 16 < NH) LOADE(uA, h0 + 16);
    CHUNK(uB, h0 + 8);
  }
#undef LOADE
#undef CHUNK

  const int k = k0 + t;
  const float p0 = (k < V) ? exp2f(-L2E2 * (acc0 + SN)) : 0.f;
  const float p1 = (k < V) ? exp2f(-L2E2 * (acc1 + SN)) : 0.f;
  const ushort u0 = f2bf(p0), u1 = f2bf(p1);
  Pb[(size_t)(b * NQ + q0) * NK + k] = u0;
  Pb[(size_t)(b * NQ + q0 + 1) * NK + k] = u1;

  float s0 = wave_rsum(bf2f(u0));
  float s1 = wave_rsum(bf2f(u1));
  if (lane == 0) { red[wid] = s0; red[4 + wid] = s1; }
  __syncthreads();
  if (t == 0) {
    atomicAdd(&rowsum[b * NQ + q0], red[0] + red[1] + red[2] + red[3]);
    atomicAdd(&rowsum[b * NQ + q0 + 1], red[4] + red[5] + red[6] + red[7]);
  }
}

// =====================================================================
// K3 v3: PV via MFMA, depth-2 ping-pong prefetch.
// out[q][v] = (sum_k Pb[q,k]*VhT[v,k]) / rowsum[q].
// grid (8 qt, 16 vt, 8 b), 128 thr = 2 waves; wave w -> v-cols vt*32+w*16.
// A-buf holds even k-steps, B-buf odd; Pb is 0 beyond V.
// =====================================================================
__global__ __launch_bounds__(128) void pv_mfma_kernel(
    const ushort* __restrict__ Pb, const ushort* __restrict__ VhT,
    const float* __restrict__ rowsum, const int* __restrict__ valid_lens,
    float* __restrict__ out) {
  const int w = threadIdx.x >> 6;
  const int lane = threadIdx.x & 63;
  const int lr = lane & 15, lg = lane >> 4;
  const int qt = blockIdx.x, vt = blockIdx.y, b = blockIdx.z;
  const int V = valid_lens[b];
  const int Kt = (V + 31) >> 5;
  const int q0 = qt * 16;
  const int v0 = vt * 32 + w * 16;
  const ushort* pp = Pb + (size_t)(b * NQ + q0 + lr) * NK + lg * 8;
  const ushort* vp = VhT + (size_t)(b * NV + v0 + lr) * NK + lg * 8;

  floatx4 accA = (floatx4){0.f, 0.f, 0.f, 0.f};
  floatx4 accB = (floatx4){0.f, 0.f, 0.f, 0.f};
  short8v pa, va, pb, vb;

  pa = *(const short8v*)&pp[0];
  va = *(const short8v*)&vp[0];
  if (Kt > 1) {
    pb = *(const short8v*)&pp[32];
    vb = *(const short8v*)&vp[32];
  }
  int s = 0;
  while (s + 2 <= Kt) {
    accA = __builtin_amdgcn_mfma_f32_16x16x32_bf16(pa, va, accA, 0, 0, 0);
    if (s + 2 < Kt) {
      pa = *(const short8v*)&pp[(size_t)(s + 2) * 32];
      va = *(const short8v*)&vp[(size_t)(s + 2) * 32];
    }
    accB = __builtin_amdgcn_mfma_f32_16x16x32_bf16(pb, vb, accB, 0, 0, 0);
    if (s + 3 < Kt) {
      pb = *(const short8v*)&pp[(size_t)(s + 3) * 32];
      vb = *(const short8v*)&vp[(size_t)(s + 3) * 32];
    }
    s += 2;
  }
  if (s < Kt)  // odd tail (even index, lives in A-buf)
    accA = __builtin_amdgcn_mfma_f32_16x16x32_bf16(pa, va, accA, 0, 0, 0);

#pragma unroll
  for (int reg = 0; reg < 4; ++reg) {
    const int row = b * NQ + q0 + lg * 4 + reg;
    const float rs = __builtin_amdgcn_rcpf(rowsum[row]);
    out[(size_t)row * NV + v0 + lr] = (accA[reg] + accB[reg]) * rs;
  }
}

// =====================================================================
extern "C" void kernel_launch(void* const* d_in, const int* in_sizes, int n_in,
                              void* d_out, int out_size, void* d_ws, size_t ws_size,
                              hipStream_t stream) {
  const float* queries = (const float*)d_in[0];
  const float* keys    = (const float*)d_in[1];
  const float* values  = (const float*)d_in[2];
  const int*   vlens   = (const int*)d_in[3];
  const float* Wq      = (const float*)d_in[4];
  const float* Wk      = (const float*)d_in[5];
  const float* wv      = (const float*)d_in[6];
  float* out = (float*)d_out;

  char* base = (char*)d_ws;
  ushort* WtQh = (ushort*)base;                       // 4 x 256KB = 1MB
  ushort* WtQl = WtQh + NH * ND;
  ushort* WtKh = WtQl + NH * ND;
  ushort* WtKl = WtKh + NH * ND;
  float*  Eq   = (float*)(base + (1 << 20));          // 1MB
  ushort* EkTb = (ushort*)(base + (2 << 20));         // 4MB
  ushort* Pb   = (ushort*)(base + (6 << 20));         // 2MB
  ushort* VhT  = (ushort*)(base + (8 << 20));         // 8MB
  float*  rowsum = (float*)(base + (16 << 20));       // 4KB
  // total 16MB + 4KB

  hipMemsetAsync(rowsum, 0, NB * NQ * sizeof(float), stream);
  splitw_kernel<<<dim3(256), dim3(256), 0, stream>>>(Wq, Wk, WtQh, WtQl, WtKh, WtKl);
  convert_v_kernel<<<dim3(32, 16, 8), dim3(256), 0, stream>>>(values, vlens, VhT);
  proj_mfma_kernel<<<dim3(576), dim3(256), 0, stream>>>(
      queries, keys, WtQh, WtQl, WtKh, WtKl, vlens, Eq, EkTb);
  score_kernel<<<dim3(64, 4, 8), dim3(256), 0, stream>>>(
      Eq, EkTb, wv, vlens, Pb, rowsum);
  pv_mfma_kernel<<<dim3(8, 16, 8), dim3(128), 0, stream>>>(
      Pb, VhT, rowsum, vlens, out);
}

// Round 6
// 153.765 us; speedup vs baseline: 1.1799x; 1.1799x over previous
//
#include <hip/hip_runtime.h>
#include <math.h>

#define NB 8
#define NQ 128
#define NK 1024
#define ND 512   // QK_DIM
#define NH 256   // HID
#define NV 512   // VDIM

typedef __attribute__((ext_vector_type(8))) short short8v;   // 8 bf16
typedef __attribute__((ext_vector_type(4))) float floatx4;

// Packed MFMA-fragment layout (the central change this round):
//   For a matrix consumed as 16-wide MFMA fragments with k-step 32, element
//   (col, d) lives at  blk = (col>>4)*NKSTEPS + (d>>5)
//                      lane = (col&15) | (((d>>3)&3)<<4),  j = d&7
//                      addr = blk*BLKSZ + lane*8 + j
//   A wave's fragment load is then lane*8 contiguous -> 64x16B = 1KB
//   coalesced (1 line-request chain instead of a 16-line gather).

// ---------- bf16 helpers (RNE) ----------
__device__ __forceinline__ ushort f2bf(float f) {
  union { float f; unsigned u; } v; v.f = f;
  unsigned r = (v.u + 0x7FFF + ((v.u >> 16) & 1)) >> 16;
  return (ushort)r;
}
__device__ __forceinline__ float bf2f(ushort b) {
  union { unsigned u; float f; } v; v.u = ((unsigned)b) << 16;
  return v.f;
}
__device__ __forceinline__ float wave_rsum(float v) {
#pragma unroll
  for (int off = 32; off; off >>= 1) v += __shfl_xor(v, off);
  return v;
}

// =====================================================================
// K0a: W [ND][NH] f32 -> packed hi/lo fragments.
// Per (cf,kk) block: 512 ushort hi then 512 ushort lo (2KB total).
// grid (256 blks, 2 sides), 64 thr; writes 2x16B coalesced per thread.
// =====================================================================
__global__ __launch_bounds__(64) void splitw_kernel(
    const float* __restrict__ Wq, const float* __restrict__ Wk,
    ushort* __restrict__ WpQ, ushort* __restrict__ WpK) {
  const int l = threadIdx.x;           // lane
  const int blk = blockIdx.x;          // cf = blk>>4, kk = blk&15
  const float* W = blockIdx.y ? Wk : Wq;
  ushort* O = blockIdx.y ? WpK : WpQ;
  const int col = ((blk >> 4) << 4) + (l & 15);
  const int dbase = (blk & 15) * 32 + ((l >> 4) << 3);
  ushort h8[8], l8[8];
#pragma unroll
  for (int j = 0; j < 8; ++j) {
    float f = W[(size_t)(dbase + j) * NH + col];
    ushort hi = f2bf(f);
    h8[j] = hi;
    l8[j] = f2bf(f - bf2f(hi));
  }
  ushort* oh = &O[(size_t)blk * 1024 + l * 8];
  *(ushort4*)&oh[0] = make_ushort4(h8[0], h8[1], h8[2], h8[3]);
  *(ushort4*)&oh[4] = make_ushort4(h8[4], h8[5], h8[6], h8[7]);
  *(ushort4*)&oh[512] = make_ushort4(l8[0], l8[1], l8[2], l8[3]);
  *(ushort4*)&oh[516] = make_ushort4(l8[4], l8[5], l8[6], l8[7]);
}

// =====================================================================
// K0b: values [b][k][v] f32 -> packed bf16 fragments Vp.
// Vp blk index = (b*32 + v>>4)*32 + k>>5, 512 ushorts per blk.
// 32x32 LDS tile: coalesced reads; packed ushort4 writes.
// =====================================================================
__global__ __launch_bounds__(256) void convert_v_kernel(
    const float* __restrict__ values, const int* __restrict__ valid_lens,
    ushort* __restrict__ Vp) {
  const int b = blockIdx.z;
  const int k0 = blockIdx.x * 32;     // gridDim.x = 32
  const int v0 = blockIdx.y * 32;     // gridDim.y = 16
  const int V = valid_lens[b];
  if (k0 >= ((V + 31) & ~31)) return;  // uniform per block
  const int t = threadIdx.x;
  __shared__ float tile[32][33];       // [k][v]
#pragma unroll
  for (int i = 0; i < 4; ++i) {
    int idx = t + 256 * i;
    int kk = idx >> 5, vv = idx & 31;
    tile[kk][vv] = values[(size_t)(b * NK + k0 + kk) * NV + v0 + vv];
  }
  __syncthreads();
  const int vv = t & 31, k4 = t >> 5;  // thread -> (v, 4 consecutive k)
  const int kr = k4 * 4;
  const size_t base = ((size_t)(b * 32 + ((v0 + vv) >> 4)) * 32 + (k0 >> 5)) * 512;
  const int off = ((vv & 15) << 3) + (((kr >> 3) & 3) << 7) + (kr & 7);
  ushort4 o;
  o.x = f2bf(tile[kr + 0][vv]);
  o.y = f2bf(tile[kr + 1][vv]);
  o.z = f2bf(tile[kr + 2][vv]);
  o.w = f2bf(tile[kr + 3][vv]);
  *(ushort4*)&Vp[base + off] = o;
}

// =====================================================================
// K1 v4: projection via split-bf16 MFMA + exp(2x) epilogue.
// W loads are packed-coalesced (1KB/instr); depth-3 W reg pipeline +
// depth-2 A-frag pipeline, statically unrolled (no dynamic indexing).
// Block 256 thr = 16 rows x 256 cols (wave w -> cols w*64..+63).
// grid 576: bx<64 q-tiles -> Eq f32; else k-tiles -> EkT bf16 (skip >=V).
// acc = Ahi*Whi + Ahi*Wlo + Alo*Whi  (~f32 precision).
// =====================================================================
__global__ __launch_bounds__(256, 2) void proj_mfma_kernel(
    const float* __restrict__ queries, const float* __restrict__ keys,
    const ushort* __restrict__ WpQ, const ushort* __restrict__ WpK,
    const int* __restrict__ valid_lens,
    float* __restrict__ Eq, ushort* __restrict__ EkTb) {
  const int t = threadIdx.x;
  const int lane = t & 63, wvid = t >> 6;
  const int lr = lane & 15, lg = lane >> 4;
  const int bx = blockIdx.x;
  const bool isQ = bx < 64;
  const float* A;
  const ushort* Wp;
  int arow0, b = 0, rin = 0;
  if (isQ) {
    A = queries; Wp = WpQ; arow0 = bx * 16;
  } else {
    int kt = bx - 64;                // 0..511
    b = kt >> 6; rin = (kt & 63) * 16;
    if (rin >= valid_lens[b]) return;
    A = keys; Wp = WpK; arow0 = b * NK + rin;
  }

  // ---- stage A tile (16x512) pre-split to bf16 hi/lo in LDS ----
  __shared__ ushort Ah[16][520];
  __shared__ ushort Al[16][520];
  {
    const float* Arow = A + (size_t)arow0 * ND;
#pragma unroll
    for (int i = 0; i < 8; ++i) {
      int e = (t + 256 * i) * 4;
      int r = e >> 9, c = e & 511;
      float4 a = *(const float4*)&Arow[e];
      ushort4 h, l;
      h.x = f2bf(a.x); l.x = f2bf(a.x - bf2f(h.x));
      h.y = f2bf(a.y); l.y = f2bf(a.y - bf2f(h.y));
      h.z = f2bf(a.z); l.z = f2bf(a.z - bf2f(h.z));
      h.w = f2bf(a.w); l.w = f2bf(a.w - bf2f(h.w));
      *(ushort4*)&Ah[r][c] = h;
      *(ushort4*)&Al[r][c] = l;
    }
  }
  __syncthreads();

  // wave's W base: blocks (wvid*4+c)*16 + kk, lane offset folded in
  const ushort* wbase = Wp + (size_t)wvid * 64 * 1024 + lane * 8;

  floatx4 acc[4];
#pragma unroll
  for (int c = 0; c < 4; ++c) acc[c] = (floatx4){0.f, 0.f, 0.f, 0.f};

  short8v wh[3][4], wl[3][4];   // depth-3 W pipeline (static idx after unroll)
  short8v ahb[2], alb[2];       // depth-2 A pipeline

#define LOADW(buf, kkv)                                                    \
  {                                                                        \
    _Pragma("unroll") for (int c = 0; c < 4; ++c) {                        \
      wh[buf][c] = *(const short8v*)&wbase[(size_t)(c * 16 + (kkv)) * 1024];        \
      wl[buf][c] = *(const short8v*)&wbase[(size_t)(c * 16 + (kkv)) * 1024 + 512];  \
    }                                                                      \
  }
#define LOADA(buf, kkv)                                                    \
  {                                                                        \
    ahb[buf] = *(const short8v*)&Ah[lr][(kkv) * 32 + lg * 8];              \
    alb[buf] = *(const short8v*)&Al[lr][(kkv) * 32 + lg * 8];              \
  }

  LOADW(0, 0);
  LOADW(1, 1);
  LOADA(0, 0);
#pragma unroll
  for (int kk = 0; kk < 16; ++kk) {
    if (kk + 2 < 16) LOADW((kk + 2) % 3, kk + 2);
    if (kk + 1 < 16) LOADA((kk + 1) & 1, kk + 1);
    const short8v ah_ = ahb[kk & 1];
    const short8v al_ = alb[kk & 1];
    const int B = kk % 3;
#pragma unroll
    for (int c = 0; c < 4; ++c) {
      acc[c] = __builtin_amdgcn_mfma_f32_16x16x32_bf16(al_, wh[B][c], acc[c], 0, 0, 0);
      acc[c] = __builtin_amdgcn_mfma_f32_16x16x32_bf16(ah_, wl[B][c], acc[c], 0, 0, 0);
      acc[c] = __builtin_amdgcn_mfma_f32_16x16x32_bf16(ah_, wh[B][c], acc[c], 0, 0, 0);
    }
  }
#undef LOADW
#undef LOADA

  const float C2 = 2.885390081777927f;  // 2*log2(e)
  if (isQ) {
#pragma unroll
    for (int c = 0; c < 4; ++c) {
      const int h = wvid * 64 + c * 16 + lr;
#pragma unroll
      for (int reg = 0; reg < 4; ++reg) {
        const int row = arow0 + lg * 4 + reg;
        float p = fminf(fmaxf(acc[c][reg], -15.f), 15.f);
        Eq[(size_t)row * NH + h] = exp2f(p * C2);
      }
    }
  } else {
#pragma unroll
    for (int c = 0; c < 4; ++c) {
      const int h = wvid * 64 + c * 16 + lr;
      ushort4 e;
      e.x = f2bf(exp2f(fminf(fmaxf(acc[c][0], -15.f), 15.f) * C2));
      e.y = f2bf(exp2f(fminf(fmaxf(acc[c][1], -15.f), 15.f) * C2));
      e.z = f2bf(exp2f(fminf(fmaxf(acc[c][2], -15.f), 15.f) * C2));
      e.w = f2bf(exp2f(fminf(fmaxf(acc[c][3], -15.f), 15.f) * C2));
      *(ushort4*)&EkTb[((size_t)(b * NH + h)) * NK + rin + lg * 4] = e;
    }
  }
}

// =====================================================================
// K2 v4: scores -> fixed-shift softmax numerators + row sums.
// p = exp2(-2log2e*(racc+SN)), SN = sum_h max(-wv_h,0)  (exact shift).
// Same compute as v3; Pb now written in PACKED fragment layout so pv's
// loads are coalesced. grid (64 q-pairs, 4 kt, 8 b), 256 thr.
// =====================================================================
__global__ __launch_bounds__(256, 2) void score_kernel(
    const float* __restrict__ Eq, const ushort* __restrict__ EkTb,
    const float* __restrict__ wvp, const int* __restrict__ valid_lens,
    ushort* __restrict__ Pbp, float* __restrict__ rowsum) {
  const int b = blockIdx.z;
  const int V = valid_lens[b];
  const int k0 = blockIdx.y * 256;
  if (k0 >= V) return;
  const int t = threadIdx.x;
  const int q0 = blockIdx.x * 2;
  const int lane = t & 63, wid = t >> 6;
  const float L2E2 = 2.8853900817779268f;  // 2*log2(e)

  __shared__ __align__(16) float eqs[2][NH];
  __shared__ __align__(16) float wvs[NH];
  __shared__ float red[8];

  if (t < 128)
    ((float4*)eqs)[t] = ((const float4*)&Eq[(size_t)(b * NQ + q0) * NH])[t];
  wvs[t] = wvp[t];
  __syncthreads();

  float mn = wave_rsum(fminf(wvs[t], 0.f));
  if (lane == 0) red[wid] = mn;
  __syncthreads();
  const float SN = -(red[0] + red[1] + red[2] + red[3]);
  __syncthreads();

  const ushort* ek = EkTb + (size_t)b * NH * NK + k0 + t;
  float acc0 = 0.f, acc1 = 0.f;

  ushort uA[8], uB[8];
#define LOADE(u, h0)                                                      \
  {                                                                       \
    _Pragma("unroll") for (int j = 0; j < 8; ++j)                         \
        u[j] = ek[(size_t)((h0) + j) * NK];                               \
  }
#define CHUNK(u, h0)                                                      \
  {                                                                       \
    float e0[8], e1[8], w8[8];                                            \
    *(float4*)&e0[0] = *(const float4*)&eqs[0][(h0)];                     \
    *(float4*)&e0[4] = *(const float4*)&eqs[0][(h0) + 4];                 \
    *(float4*)&e1[0] = *(const float4*)&eqs[1][(h0)];                     \
    *(float4*)&e1[4] = *(const float4*)&eqs[1][(h0) + 4];                 \
    *(float4*)&w8[0] = *(const float4*)&wvs[(h0)];                        \
    *(float4*)&w8[4] = *(const float4*)&wvs[(h0) + 4];                    \
    _Pragma("unroll") for (int j = 0; j < 8; ++j) {                       \
      const float ev = bf2f(u[j]);                                        \
      acc0 += w8[j] * __builtin_amdgcn_rcpf(__builtin_fmaf(e0[j], ev, 1.f)); \
      acc1 += w8[j] * __builtin_amdgcn_rcpf(__builtin_fmaf(e1[j], ev, 1.f)); \
    }                                                                     \
  }

  LOADE(uA, 0);
#pragma unroll 1
  for (int h0 = 0; h0 < NH; h0 += 16) {
    LOADE(uB, h0 + 8);
    CHUNK(uA, h0);
    if (h0 + 16 < NH) LOADE(uA, h0 + 16);
    CHUNK(uB, h0 + 8);
  }
#undef LOADE
#undef CHUNK

  const int k = k0 + t;
  const float p0 = (k < V) ? exp2f(-L2E2 * (acc0 + SN)) : 0.f;
  const float p1 = (k < V) ? exp2f(-L2E2 * (acc1 + SN)) : 0.f;
  const ushort u0 = f2bf(p0), u1 = f2bf(p1);

  // packed write: blk = (b*8 + q>>4)*32 + k>>5 ; off = (q&15)*8 + ((k>>3)&3)*128 + (k&7)
  {
    const size_t blk0 = ((size_t)(b * 8 + (q0 >> 4)) * 32 + (k0 >> 5) + (t >> 5)) * 512;
    const int offk = (((t >> 3) & 3) << 7) + (t & 7);
    Pbp[blk0 + ((q0 & 15) << 3) + offk] = u0;
    Pbp[blk0 + (((q0 + 1) & 15) << 3) + offk] = u1;
  }

  float s0 = wave_rsum(bf2f(u0));
  float s1 = wave_rsum(bf2f(u1));
  if (lane == 0) { red[wid] = s0; red[4 + wid] = s1; }
  __syncthreads();
  if (t == 0) {
    atomicAdd(&rowsum[b * NQ + q0], red[0] + red[1] + red[2] + red[3]);
    atomicAdd(&rowsum[b * NQ + q0 + 1], red[4] + red[5] + red[6] + red[7]);
  }
}

// =====================================================================
// K3 v4: PV via MFMA on packed operands, depth-4 named-buffer pipeline.
// out[q][v] = (sum_k Pbp[q,k]*Vp[v,k]) / rowsum[q].
// grid (8 qt, 16 vt2, 8 b), 128 thr = 2 waves; wave w -> vt = vt2*2+w.
// Kt padded to x4: pad kk's read zeroed Pb (proven <= ceil256(V)/32).
// =====================================================================
__global__ __launch_bounds__(128, 2) void pv_mfma_kernel(
    const ushort* __restrict__ Pbp, const ushort* __restrict__ Vp,
    const float* __restrict__ rowsum, const int* __restrict__ valid_lens,
    float* __restrict__ out) {
  const int w = threadIdx.x >> 6;
  const int lane = threadIdx.x & 63;
  const int lr = lane & 15, lg = lane >> 4;
  const int qt = blockIdx.x, vt2 = blockIdx.y, b = blockIdx.z;
  const int V = valid_lens[b];
  const int Kt4 = (((V + 31) >> 5) + 3) & ~3;
  const int vt = vt2 * 2 + w;
  const ushort* pbase = Pbp + ((size_t)(b * 8 + qt) * 32) * 512 + lane * 8;
  const ushort* vbase = Vp + ((size_t)(b * 32 + vt) * 32) * 512 + lane * 8;

#define LP(s) (*(const short8v*)&pbase[(size_t)(s) * 512])
#define LV(s) (*(const short8v*)&vbase[(size_t)(s) * 512])

  floatx4 acc0 = (floatx4){0.f, 0.f, 0.f, 0.f};
  floatx4 acc1 = (floatx4){0.f, 0.f, 0.f, 0.f};
  short8v pA, vA, pB, vB, pC, vC, pD, vD;
  pA = LP(0); vA = LV(0);          // Kt4 >= 4 always
  pB = LP(1); vB = LV(1);
  pC = LP(2); vC = LV(2);
  for (int s = 0; s < Kt4; s += 4) {
    pD = LP(s + 3); vD = LV(s + 3);
    acc0 = __builtin_amdgcn_mfma_f32_16x16x32_bf16(pA, vA, acc0, 0, 0, 0);
    if (s + 4 < Kt4) { pA = LP(s + 4); vA = LV(s + 4); }
    acc1 = __builtin_amdgcn_mfma_f32_16x16x32_bf16(pB, vB, acc1, 0, 0, 0);
    if (s + 5 < Kt4) { pB = LP(s + 5); vB = LV(s + 5); }
    acc0 = __builtin_amdgcn_mfma_f32_16x16x32_bf16(pC, vC, acc0, 0, 0, 0);
    if (s + 6 < Kt4) { pC = LP(s + 6); vC = LV(s + 6); }
    acc1 = __builtin_amdgcn_mfma_f32_16x16x32_bf16(pD, vD, acc1, 0, 0, 0);
  }
#undef LP
#undef LV

#pragma unroll
  for (int reg = 0; reg < 4; ++reg) {
    const int row = b * NQ + qt * 16 + lg * 4 + reg;
    const float rs = __builtin_amdgcn_rcpf(rowsum[row]);
    out[(size_t)row * NV + vt * 16 + lr] = (acc0[reg] + acc1[reg]) * rs;
  }
}

// =====================================================================
extern "C" void kernel_launch(void* const* d_in, const int* in_sizes, int n_in,
                              void* d_out, int out_size, void* d_ws, size_t ws_size,
                              hipStream_t stream) {
  const float* queries = (const float*)d_in[0];
  const float* keys    = (const float*)d_in[1];
  const float* values  = (const float*)d_in[2];
  const int*   vlens   = (const int*)d_in[3];
  const float* Wq      = (const float*)d_in[4];
  const float* Wk      = (const float*)d_in[5];
  const float* wv      = (const float*)d_in[6];
  float* out = (float*)d_out;

  char* base = (char*)d_ws;
  ushort* WpQ  = (ushort*)base;                       // 512KB packed hi/lo
  ushort* WpK  = WpQ + 256 * 1024;                    // 512KB
  float*  Eq   = (float*)(base + (1 << 20));          // 1MB
  ushort* EkTb = (ushort*)(base + (2 << 20));         // 4MB
  ushort* Pbp  = (ushort*)(base + (6 << 20));         // 2MB packed
  ushort* Vp   = (ushort*)(base + (8 << 20));         // 8MB packed
  float*  rowsum = (float*)(base + (16 << 20));       // 4KB
  // total 16MB + 4KB

  hipMemsetAsync(rowsum, 0, NB * NQ * sizeof(float), stream);
  splitw_kernel<<<dim3(256, 2), dim3(64), 0, stream>>>(Wq, Wk, WpQ, WpK);
  convert_v_kernel<<<dim3(32, 16, 8), dim3(256), 0, stream>>>(values, vlens, Vp);
  proj_mfma_kernel<<<dim3(576), dim3(256), 0, stream>>>(
      queries, keys, WpQ, WpK, vlens, Eq, EkTb);
  score_kernel<<<dim3(64, 4, 8), dim3(256), 0, stream>>>(
      Eq, EkTb, wv, vlens, Pbp, rowsum);
  pv_mfma_kernel<<<dim3(8, 16, 8), dim3(128), 0, stream>>>(
      Pbp, Vp, rowsum, vlens, out);
}

// Round 7
// 150.541 us; speedup vs baseline: 1.2052x; 1.0214x over previous
//
#include <hip/hip_runtime.h>
#include <math.h>

#define NB 8
#define NQ 128
#define NK 1024
#define ND 512   // QK_DIM
#define NH 256   // HID
#define NV 512   // VDIM

typedef __attribute__((ext_vector_type(8))) short short8v;   // 8 bf16
typedef __attribute__((ext_vector_type(4))) float floatx4;

// Packed MFMA-fragment layout: for a matrix consumed as 16-wide MFMA
// fragments with k-step 32, element (col,d) lives at
//   blk = (col>>4)*NKSTEPS + (d>>5); lane = (col&15)|(((d>>3)&3)<<4); j = d&7
//   addr = blk*1024(+512 for lo half) + lane*8 + j
// -> a wave's fragment load/Store is 64x16B = 1KB contiguous, and is the
// exact wave-linear order global_load_lds writes (base + lane*16B).

// ---------- bf16 helpers (RNE) ----------
__device__ __forceinline__ ushort f2bf(float f) {
  union { float f; unsigned u; } v; v.f = f;
  unsigned r = (v.u + 0x7FFF + ((v.u >> 16) & 1)) >> 16;
  return (ushort)r;
}
__device__ __forceinline__ float bf2f(ushort b) {
  union { unsigned u; float f; } v; v.u = ((unsigned)b) << 16;
  return v.f;
}
__device__ __forceinline__ float wave_rsum(float v) {
#pragma unroll
  for (int off = 32; off; off >>= 1) v += __shfl_xor(v, off);
  return v;
}

// =====================================================================
// K0a: W [ND][NH] f32 -> packed hi/lo fragments; also zeroes rowsum
// (folded here to drop the separate memset dispatch).
// =====================================================================
__global__ __launch_bounds__(64) void splitw_kernel(
    const float* __restrict__ Wq, const float* __restrict__ Wk,
    ushort* __restrict__ WpQ, ushort* __restrict__ WpK,
    float* __restrict__ rowsum) {
  const int l = threadIdx.x;           // lane
  const int blk = blockIdx.x;          // cf = blk>>4, kk = blk&15
  if (blockIdx.y == 0 && blk < 16) rowsum[blk * 64 + l] = 0.f;  // 1024 = NB*NQ
  const float* W = blockIdx.y ? Wk : Wq;
  ushort* O = blockIdx.y ? WpK : WpQ;
  const int col = ((blk >> 4) << 4) + (l & 15);
  const int dbase = (blk & 15) * 32 + ((l >> 4) << 3);
  ushort h8[8], l8[8];
#pragma unroll
  for (int j = 0; j < 8; ++j) {
    float f = W[(size_t)(dbase + j) * NH + col];
    ushort hi = f2bf(f);
    h8[j] = hi;
    l8[j] = f2bf(f - bf2f(hi));
  }
  ushort* oh = &O[(size_t)blk * 1024 + l * 8];
  *(ushort4*)&oh[0] = make_ushort4(h8[0], h8[1], h8[2], h8[3]);
  *(ushort4*)&oh[4] = make_ushort4(h8[4], h8[5], h8[6], h8[7]);
  *(ushort4*)&oh[512] = make_ushort4(l8[0], l8[1], l8[2], l8[3]);
  *(ushort4*)&oh[516] = make_ushort4(l8[4], l8[5], l8[6], l8[7]);
}

// =====================================================================
// K0b: values [b][k][v] f32 -> packed bf16 fragments Vp.
// blk index = (b*32 + v>>4)*32 + k>>5, 512 ushorts per blk.
// =====================================================================
__global__ __launch_bounds__(256) void convert_v_kernel(
    const float* __restrict__ values, const int* __restrict__ valid_lens,
    ushort* __restrict__ Vp) {
  const int b = blockIdx.z;
  const int k0 = blockIdx.x * 32;     // gridDim.x = 32
  const int v0 = blockIdx.y * 32;     // gridDim.y = 16
  const int V = valid_lens[b];
  if (k0 >= ((V + 31) & ~31)) return;  // uniform per block
  const int t = threadIdx.x;
  __shared__ float tile[32][33];       // [k][v]
#pragma unroll
  for (int i = 0; i < 4; ++i) {
    int idx = t + 256 * i;
    int kk = idx >> 5, vv = idx & 31;
    tile[kk][vv] = values[(size_t)(b * NK + k0 + kk) * NV + v0 + vv];
  }
  __syncthreads();
  const int vv = t & 31, k4 = t >> 5;
  const int kr = k4 * 4;
  const size_t base = ((size_t)(b * 32 + ((v0 + vv) >> 4)) * 32 + (k0 >> 5)) * 512;
  const int off = ((vv & 15) << 3) + (((kr >> 3) & 3) << 7) + (kr & 7);
  ushort4 o;
  o.x = f2bf(tile[kr + 0][vv]);
  o.y = f2bf(tile[kr + 1][vv]);
  o.z = f2bf(tile[kr + 2][vv]);
  o.w = f2bf(tile[kr + 3][vv]);
  *(ushort4*)&Vp[base + off] = o;
}

// =====================================================================
// K1 v5: projection via split-bf16 MFMA + exp(2x) epilogue.
// W streamed into an LDS 3-buffer ring with global_load_lds (async,
// VGPR-free) + counted s_waitcnt vmcnt(N) (never 0 mid-loop): depth-2
// prefetch covers L2 latency regardless of register allocation.
// Each wave owns its ring region -> no barriers in the K-loop.
// Block 256 thr = 16 rows x 256 cols; grid 576 (64 q-tiles + 512 k-tiles,
// k-tiles beyond valid_len exit). acc = Ahi*Whi + Ahi*Wlo + Alo*Whi.
// =====================================================================
__global__ __launch_bounds__(256, 1) void proj_mfma_kernel(
    const float* __restrict__ queries, const float* __restrict__ keys,
    const ushort* __restrict__ WpQ, const ushort* __restrict__ WpK,
    const int* __restrict__ valid_lens,
    float* __restrict__ Eq, ushort* __restrict__ EkTb) {
  const int t = threadIdx.x;
  const int lane = t & 63, wvid = t >> 6;
  const int lr = lane & 15, lg = lane >> 4;
  const int bx = blockIdx.x;
  const bool isQ = bx < 64;
  const float* A;
  const ushort* Wp;
  int arow0, b = 0, rin = 0;
  if (isQ) {
    A = queries; Wp = WpQ; arow0 = bx * 16;
  } else {
    int kt = bx - 64;                // 0..511
    b = kt >> 6; rin = (kt & 63) * 16;
    if (rin >= valid_lens[b]) return;
    A = keys; Wp = WpK; arow0 = b * NK + rin;
  }

  __shared__ ushort Wlds[3][4][8][512];  // ring x wave x frag(c*2+half) x 1KB
  __shared__ ushort Ah[16][520];
  __shared__ ushort Al[16][520];

  // issue 8 async W loads for K-step kkv into ring slot `buf`
#define ISSUE(buf, kkv)                                                        \
  {                                                                            \
    _Pragma("unroll") for (int f = 0; f < 8; ++f) {                            \
      const ushort* g = &Wp[((size_t)((wvid * 4 + (f >> 1)) * 16 + (kkv))      \
                             << 10) + ((f & 1) << 9) + lane * 8];              \
      __builtin_amdgcn_global_load_lds(                                        \
          (const __attribute__((address_space(1))) void*)g,                    \
          (__attribute__((address_space(3))) void*)&Wlds[buf][wvid][f][0],     \
          16, 0, 0);                                                           \
    }                                                                          \
  }

  ISSUE(0, 0);
  ISSUE(1, 1);   // prefetch first two K-steps; they land under the A-stage

  {  // ---- stage A tile (16x512) pre-split to bf16 hi/lo in LDS ----
    const float* Arow = A + (size_t)arow0 * ND;
#pragma unroll
    for (int i = 0; i < 8; ++i) {
      int e = (t + 256 * i) * 4;
      int r = e >> 9, c = e & 511;
      float4 a = *(const float4*)&Arow[e];
      ushort4 h, l;
      h.x = f2bf(a.x); l.x = f2bf(a.x - bf2f(h.x));
      h.y = f2bf(a.y); l.y = f2bf(a.y - bf2f(h.y));
      h.z = f2bf(a.z); l.z = f2bf(a.z - bf2f(h.z));
      h.w = f2bf(a.w); l.w = f2bf(a.w - bf2f(h.w));
      *(ushort4*)&Ah[r][c] = h;
      *(ushort4*)&Al[r][c] = l;
    }
  }
  __syncthreads();

  floatx4 acc[4];
#pragma unroll
  for (int c = 0; c < 4; ++c) acc[c] = (floatx4){0.f, 0.f, 0.f, 0.f};

#pragma unroll
  for (int kk = 0; kk < 16; ++kk) {
    if (kk + 2 < 16) ISSUE((kk + 2) % 3, kk + 2);
    // counted waits: keep 2 batches (16 loads) in flight, never drain mid-loop
    if (kk < 14)      asm volatile("s_waitcnt vmcnt(16)" ::: "memory");
    else if (kk == 14) asm volatile("s_waitcnt vmcnt(8)" ::: "memory");
    else               asm volatile("s_waitcnt vmcnt(0)" ::: "memory");
    const short8v ah_ = *(const short8v*)&Ah[lr][kk * 32 + lg * 8];
    const short8v al_ = *(const short8v*)&Al[lr][kk * 32 + lg * 8];
#pragma unroll
    for (int c = 0; c < 4; ++c) {
      const short8v wh_ = *(const short8v*)&Wlds[kk % 3][wvid][c * 2 + 0][lane * 8];
      const short8v wl_ = *(const short8v*)&Wlds[kk % 3][wvid][c * 2 + 1][lane * 8];
      acc[c] = __builtin_amdgcn_mfma_f32_16x16x32_bf16(al_, wh_, acc[c], 0, 0, 0);
      acc[c] = __builtin_amdgcn_mfma_f32_16x16x32_bf16(ah_, wl_, acc[c], 0, 0, 0);
      acc[c] = __builtin_amdgcn_mfma_f32_16x16x32_bf16(ah_, wh_, acc[c], 0, 0, 0);
    }
  }
#undef ISSUE

  const float C2 = 2.885390081777927f;  // 2*log2(e)
  if (isQ) {
#pragma unroll
    for (int c = 0; c < 4; ++c) {
      const int h = wvid * 64 + c * 16 + lr;
#pragma unroll
      for (int reg = 0; reg < 4; ++reg) {
        const int row = arow0 + lg * 4 + reg;
        float p = fminf(fmaxf(acc[c][reg], -15.f), 15.f);
        Eq[(size_t)row * NH + h] = exp2f(p * C2);
      }
    }
  } else {
#pragma unroll
    for (int c = 0; c < 4; ++c) {
      const int h = wvid * 64 + c * 16 + lr;
      ushort4 e;
      e.x = f2bf(exp2f(fminf(fmaxf(acc[c][0], -15.f), 15.f) * C2));
      e.y = f2bf(exp2f(fminf(fmaxf(acc[c][1], -15.f), 15.f) * C2));
      e.z = f2bf(exp2f(fminf(fmaxf(acc[c][2], -15.f), 15.f) * C2));
      e.w = f2bf(exp2f(fminf(fmaxf(acc[c][3], -15.f), 15.f) * C2));
      *(ushort4*)&EkTb[((size_t)(b * NH + h)) * NK + rin + lg * 4] = e;
    }
  }
}

// =====================================================================
// K2 v5: scores -> fixed-shift softmax numerators + row sums, 4 q/block.
// p = exp2(-2log2e*(racc+SN)), SN = sum_h max(-wv_h,0)  (exact shift).
// 4 q rows halve Ek traffic per FLOP; rcp chain is the intended floor.
// grid (32 q-quads, 4 kt, 8 b), 256 thr; Pb written packed for pv.
// =====================================================================
__global__ __launch_bounds__(256, 2) void score_kernel(
    const float* __restrict__ Eq, const ushort* __restrict__ EkTb,
    const float* __restrict__ wvp, const int* __restrict__ valid_lens,
    ushort* __restrict__ Pbp, float* __restrict__ rowsum) {
  const int b = blockIdx.z;
  const int V = valid_lens[b];
  const int k0 = blockIdx.y * 256;
  if (k0 >= V) return;
  const int t = threadIdx.x;
  const int q0 = blockIdx.x * 4;
  const int lane = t & 63, wid = t >> 6;
  const float L2E2 = 2.8853900817779268f;  // 2*log2(e)

  __shared__ __align__(16) float eqs[4][NH];
  __shared__ __align__(16) float wvs[NH];
  __shared__ float red[20];

  ((float4*)eqs)[t] = ((const float4*)&Eq[(size_t)(b * NQ + q0) * NH])[t];
  wvs[t] = wvp[t];
  __syncthreads();

  float mn = wave_rsum(fminf(wvs[t], 0.f));
  if (lane == 0) red[wid] = mn;
  __syncthreads();
  const float SN = -(red[0] + red[1] + red[2] + red[3]);

  const ushort* ek = EkTb + (size_t)b * NH * NK + k0 + t;
  float a0 = 0.f, a1 = 0.f, a2 = 0.f, a3 = 0.f;

  ushort uA[8], uB[8];
#define LOADE(u, h0)                                                      \
  {                                                                       \
    _Pragma("unroll") for (int j = 0; j < 8; ++j)                         \
        u[j] = ek[(size_t)((h0) + j) * NK];                               \
  }
#define CHUNK(u, h0)                                                      \
  {                                                                       \
    float e0[8], e1[8], e2[8], e3[8], w8[8];                              \
    *(float4*)&e0[0] = *(const float4*)&eqs[0][(h0)];                     \
    *(float4*)&e0[4] = *(const float4*)&eqs[0][(h0) + 4];                 \
    *(float4*)&e1[0] = *(const float4*)&eqs[1][(h0)];                     \
    *(float4*)&e1[4] = *(const float4*)&eqs[1][(h0) + 4];                 \
    *(float4*)&e2[0] = *(const float4*)&eqs[2][(h0)];                     \
    *(float4*)&e2[4] = *(const float4*)&eqs[2][(h0) + 4];                 \
    *(float4*)&e3[0] = *(const float4*)&eqs[3][(h0)];                     \
    *(float4*)&e3[4] = *(const float4*)&eqs[3][(h0) + 4];                 \
    *(float4*)&w8[0] = *(const float4*)&wvs[(h0)];                        \
    *(float4*)&w8[4] = *(const float4*)&wvs[(h0) + 4];                    \
    _Pragma("unroll") for (int j = 0; j < 8; ++j) {                       \
      const float ev = bf2f(u[j]);                                        \
      a0 += w8[j] * __builtin_amdgcn_rcpf(__builtin_fmaf(e0[j], ev, 1.f)); \
      a1 += w8[j] * __builtin_amdgcn_rcpf(__builtin_fmaf(e1[j], ev, 1.f)); \
      a2 += w8[j] * __builtin_amdgcn_rcpf(__builtin_fmaf(e2[j], ev, 1.f)); \
      a3 += w8[j] * __builtin_amdgcn_rcpf(__builtin_fmaf(e3[j], ev, 1.f)); \
    }                                                                     \
  }

  LOADE(uA, 0);
#pragma unroll 1
  for (int h0 = 0; h0 < NH; h0 += 16) {
    LOADE(uB, h0 + 8);
    CHUNK(uA, h0);
    if (h0 + 16 < NH) LOADE(uA, h0 + 16);
    CHUNK(uB, h0 + 8);
  }
#undef LOADE
#undef CHUNK

  const int k = k0 + t;
  const bool ok = (k < V);
  float p[4];
  p[0] = ok ? exp2f(-L2E2 * (a0 + SN)) : 0.f;
  p[1] = ok ? exp2f(-L2E2 * (a1 + SN)) : 0.f;
  p[2] = ok ? exp2f(-L2E2 * (a2 + SN)) : 0.f;
  p[3] = ok ? exp2f(-L2E2 * (a3 + SN)) : 0.f;

  const size_t blk0 = ((size_t)(b * 8 + (q0 >> 4)) * 32 + (k0 >> 5) + (t >> 5)) * 512;
  const int offk = (((t >> 3) & 3) << 7) + (t & 7);
#pragma unroll
  for (int i = 0; i < 4; ++i) {
    const ushort ui = f2bf(p[i]);
    Pbp[blk0 + (((q0 + i) & 15) << 3) + offk] = ui;
    float s = wave_rsum(bf2f(ui));
    if (lane == 0) red[4 + i * 4 + wid] = s;
  }
  __syncthreads();
  if (t < 4)
    atomicAdd(&rowsum[b * NQ + q0 + t],
              red[4 + t * 4] + red[5 + t * 4] + red[6 + t * 4] + red[7 + t * 4]);
}

// =====================================================================
// K3 v4: PV via MFMA on packed operands, depth-4 named-buffer pipeline.
// out[q][v] = (sum_k Pbp[q,k]*Vp[v,k]) / rowsum[q].
// grid (8 qt, 16 vt2, 8 b), 128 thr; pad kk's read zeroed Pb (safe).
// =====================================================================
__global__ __launch_bounds__(128, 2) void pv_mfma_kernel(
    const ushort* __restrict__ Pbp, const ushort* __restrict__ Vp,
    const float* __restrict__ rowsum, const int* __restrict__ valid_lens,
    float* __restrict__ out) {
  const int w = threadIdx.x >> 6;
  const int lane = threadIdx.x & 63;
  const int lr = lane & 15, lg = lane >> 4;
  const int qt = blockIdx.x, vt2 = blockIdx.y, b = blockIdx.z;
  const int V = valid_lens[b];
  const int Kt4 = (((V + 31) >> 5) + 3) & ~3;
  const int vt = vt2 * 2 + w;
  const ushort* pbase = Pbp + ((size_t)(b * 8 + qt) * 32) * 512 + lane * 8;
  const ushort* vbase = Vp + ((size_t)(b * 32 + vt) * 32) * 512 + lane * 8;

#define LP(s) (*(const short8v*)&pbase[(size_t)(s) * 512])
#define LV(s) (*(const short8v*)&vbase[(size_t)(s) * 512])

  floatx4 acc0 = (floatx4){0.f, 0.f, 0.f, 0.f};
  floatx4 acc1 = (floatx4){0.f, 0.f, 0.f, 0.f};
  short8v pA, vA, pB, vB, pC, vC, pD, vD;
  pA = LP(0); vA = LV(0);          // Kt4 >= 4 always
  pB = LP(1); vB = LV(1);
  pC = LP(2); vC = LV(2);
  for (int s = 0; s < Kt4; s += 4) {
    pD = LP(s + 3); vD = LV(s + 3);
    acc0 = __builtin_amdgcn_mfma_f32_16x16x32_bf16(pA, vA, acc0, 0, 0, 0);
    if (s + 4 < Kt4) { pA = LP(s + 4); vA = LV(s + 4); }
    acc1 = __builtin_amdgcn_mfma_f32_16x16x32_bf16(pB, vB, acc1, 0, 0, 0);
    if (s + 5 < Kt4) { pB = LP(s + 5); vB = LV(s + 5); }
    acc0 = __builtin_amdgcn_mfma_f32_16x16x32_bf16(pC, vC, acc0, 0, 0, 0);
    if (s + 6 < Kt4) { pC = LP(s + 6); vC = LV(s + 6); }
    acc1 = __builtin_amdgcn_mfma_f32_16x16x32_bf16(pD, vD, acc1, 0, 0, 0);
  }
#undef LP
#undef LV

#pragma unroll
  for (int reg = 0; reg < 4; ++reg) {
    const int row = b * NQ + qt * 16 + lg * 4 + reg;
    const float rs = __builtin_amdgcn_rcpf(rowsum[row]);
    out[(size_t)row * NV + vt * 16 + lr] = (acc0[reg] + acc1[reg]) * rs;
  }
}

// =====================================================================
extern "C" void kernel_launch(void* const* d_in, const int* in_sizes, int n_in,
                              void* d_out, int out_size, void* d_ws, size_t ws_size,
                              hipStream_t stream) {
  const float* queries = (const float*)d_in[0];
  const float* keys    = (const float*)d_in[1];
  const float* values  = (const float*)d_in[2];
  const int*   vlens   = (const int*)d_in[3];
  const float* Wq      = (const float*)d_in[4];
  const float* Wk      = (const float*)d_in[5];
  const float* wv      = (const float*)d_in[6];
  float* out = (float*)d_out;

  char* base = (char*)d_ws;
  ushort* WpQ  = (ushort*)base;                       // 512KB packed hi/lo
  ushort* WpK  = WpQ + 256 * 1024;                    // 512KB
  float*  Eq   = (float*)(base + (1 << 20));          // 1MB
  ushort* EkTb = (ushort*)(base + (2 << 20));         // 4MB
  ushort* Pbp  = (ushort*)(base + (6 << 20));         // 2MB packed
  ushort* Vp   = (ushort*)(base + (8 << 20));         // 8MB packed
  float*  rowsum = (float*)(base + (16 << 20));       // 4KB
  // total 16MB + 4KB

  splitw_kernel<<<dim3(256, 2), dim3(64), 0, stream>>>(Wq, Wk, WpQ, WpK, rowsum);
  convert_v_kernel<<<dim3(32, 16, 8), dim3(256), 0, stream>>>(values, vlens, Vp);
  proj_mfma_kernel<<<dim3(576), dim3(256), 0, stream>>>(
      queries, keys, WpQ, WpK, vlens, Eq, EkTb);
  score_kernel<<<dim3(32, 4, 8), dim3(256), 0, stream>>>(
      Eq, EkTb, wv, vlens, Pbp, rowsum);
  pv_mfma_kernel<<<dim3(8, 16, 8), dim3(128), 0, stream>>>(
      Pbp, Vp, rowsum, vlens, out);
}

// Round 8
// 148.692 us; speedup vs baseline: 1.2202x; 1.0124x over previous
//
#include <hip/hip_runtime.h>
#include <math.h>

#define NB 8
#define NQ 128
#define NK 1024
#define ND 512   // QK_DIM
#define NH 256   // HID
#define NV 512   // VDIM

typedef __attribute__((ext_vector_type(8))) short short8v;   // 8 bf16
typedef __attribute__((ext_vector_type(4))) float floatx4;

// Packed MFMA-fragment layout: for a matrix consumed as 16-wide MFMA
// fragments with k-step 32, element (col,d) lives at
//   blk = (col>>4)*16 + (d>>5); lane = (col&15)|(((d>>3)&3)<<4); j = d&7
//   addr = blk*1024 (+512 for lo half) + lane*8 + j
// -> a wave's fragment load is 64x16B = 1KB contiguous == the exact
// wave-linear order global_load_lds writes (uniform base + lane*16B).

// ---------- bf16 helpers (RNE) ----------
__device__ __forceinline__ ushort f2bf(float f) {
  union { float f; unsigned u; } v; v.f = f;
  unsigned r = (v.u + 0x7FFF + ((v.u >> 16) & 1)) >> 16;
  return (ushort)r;
}
__device__ __forceinline__ float bf2f(ushort b) {
  union { unsigned u; float f; } v; v.u = ((unsigned)b) << 16;
  return v.f;
}
__device__ __forceinline__ float wave_rsum(float v) {
#pragma unroll
  for (int off = 32; off; off >>= 1) v += __shfl_xor(v, off);
  return v;
}

// =====================================================================
// K0 prep: one launch does all preprocessing.
//  blocks [0,128)     : W q/k -> packed hi/lo fragments (512 wave-units)
//  blocks [128,2432)  : A = queries||keys -> Ap packed hi/lo fragments
//  blocks [2432,6528) : values -> Vp packed bf16 fragments
//  block  6528        : zero rowsum
// =====================================================================
__global__ __launch_bounds__(256) void prep_kernel(
    const float* __restrict__ q, const float* __restrict__ kys,
    const float* __restrict__ vals, const int* __restrict__ vl,
    const float* __restrict__ Wq, const float* __restrict__ Wk,
    ushort* __restrict__ WpQ, ushort* __restrict__ WpK,
    ushort* __restrict__ Ap, ushort* __restrict__ Vp,
    float* __restrict__ rowsum) {
  const int bi = blockIdx.x, t = threadIdx.x;
  if (bi < 128) {
    // ---- W split+pack: unit = one (mat, fragblock) per wave ----
    const int unit = (bi << 2) | (t >> 6);
    const int mat = unit >> 8, blk = unit & 255, l = t & 63;
    const float* W = mat ? Wk : Wq;
    ushort* O = mat ? WpK : WpQ;
    const int col = ((blk >> 4) << 4) + (l & 15);
    const int dbase = (blk & 15) * 32 + ((l >> 4) << 3);
    ushort h8[8], l8[8];
#pragma unroll
    for (int j = 0; j < 8; ++j) {
      float f = W[(size_t)(dbase + j) * NH + col];
      ushort hi = f2bf(f);
      h8[j] = hi;
      l8[j] = f2bf(f - bf2f(hi));
    }
    ushort* oh = &O[(size_t)blk * 1024 + l * 8];
    *(ushort4*)&oh[0] = make_ushort4(h8[0], h8[1], h8[2], h8[3]);
    *(ushort4*)&oh[4] = make_ushort4(h8[4], h8[5], h8[6], h8[7]);
    *(ushort4*)&oh[512] = make_ushort4(l8[0], l8[1], l8[2], l8[3]);
    *(ushort4*)&oh[516] = make_ushort4(l8[4], l8[5], l8[6], l8[7]);
  } else if (bi < 2432) {
    // ---- A split+pack: block = 64 rows x 32 d (one K-step) ----
    const int bi2 = bi - 128;
    const int rg = bi2 >> 4, kk = bi2 & 15;
    const int r0 = rg * 64;
    const float* src;
    int srow;
    if (r0 < 1024) { src = q; srow = r0; }
    else {
      const int rk = r0 - 1024;
      const int b = rk >> 10, rin = rk & 1023;
      if (rin >= vl[b]) return;  // uniform; Ap stays poison, never read
      src = kys; srow = rk;
    }
    const int row = t >> 2, dq = t & 3;
    const float* p = &src[(size_t)(srow + row) * ND + kk * 32 + dq * 8];
    const float4 a0 = *(const float4*)p;
    const float4 a1 = *(const float4*)(p + 4);
    ushort4 h0, l0, h1, l1;
    h0.x = f2bf(a0.x); l0.x = f2bf(a0.x - bf2f(h0.x));
    h0.y = f2bf(a0.y); l0.y = f2bf(a0.y - bf2f(h0.y));
    h0.z = f2bf(a0.z); l0.z = f2bf(a0.z - bf2f(h0.z));
    h0.w = f2bf(a0.w); l0.w = f2bf(a0.w - bf2f(h0.w));
    h1.x = f2bf(a1.x); l1.x = f2bf(a1.x - bf2f(h1.x));
    h1.y = f2bf(a1.y); l1.y = f2bf(a1.y - bf2f(h1.y));
    h1.z = f2bf(a1.z); l1.z = f2bf(a1.z - bf2f(h1.z));
    h1.w = f2bf(a1.w); l1.w = f2bf(a1.w - bf2f(h1.w));
    const size_t blkidx = ((size_t)((r0 + row) >> 4) * 16 + kk) * 1024;
    const int lp = ((row & 15) | (dq << 4)) * 8;
    *(ushort4*)&Ap[blkidx + lp] = h0;
    *(ushort4*)&Ap[blkidx + lp + 4] = h1;
    *(ushort4*)&Ap[blkidx + 512 + lp] = l0;
    *(ushort4*)&Ap[blkidx + 512 + lp + 4] = l1;
  } else if (bi < 6528) {
    // ---- values -> Vp packed (32x32 LDS transpose tile) ----
    const int bi3 = bi - 2432;
    const int b = bi3 >> 9, rest = bi3 & 511;
    const int k0 = (rest >> 4) * 32, v0 = (rest & 15) * 32;
    const int V = vl[b];
    if (k0 >= ((V + 31) & ~31)) return;
    __shared__ float tile[32][33];  // [k][v]
#pragma unroll
    for (int i = 0; i < 4; ++i) {
      int idx = t + 256 * i;
      int kk = idx >> 5, vv = idx & 31;
      tile[kk][vv] = vals[(size_t)(b * NK + k0 + kk) * NV + v0 + vv];
    }
    __syncthreads();
    const int vv = t & 31, kr = (t >> 5) * 4;
    const size_t base = ((size_t)(b * 32 + ((v0 + vv) >> 4)) * 32 + (k0 >> 5)) * 512;
    const int off = ((vv & 15) << 3) + (((kr >> 3) & 3) << 7) + (kr & 7);
    ushort4 o;
    o.x = f2bf(tile[kr + 0][vv]);
    o.y = f2bf(tile[kr + 1][vv]);
    o.z = f2bf(tile[kr + 2][vv]);
    o.w = f2bf(tile[kr + 3][vv]);
    *(ushort4*)&Vp[base + off] = o;
  } else {
    for (int i = t; i < NB * NQ; i += 256) rowsum[i] = 0.f;
  }
}

// =====================================================================
// K1 v6: projection via split-bf16 MFMA + exp(2x) epilogue.
// 1-wave blocks, 32 rows x 64 cols. All operands pre-packed bf16 hi/lo;
// W and A streamed by global_load_lds into private depth-2 LDS rings
// (24 KB total -> 6 blocks/CU = 1.5 waves/SIMD), counted vmcnt(12)
// (never 0 mid-loop), no barriers anywhere, 24 MFMA per K-step.
// grid = 288 row-pairs x 4 col-groups = 1152 blocks; key blocks beyond
// valid_len exit. acc = Ahi*Whi + Ahi*Wlo + Alo*Whi (~f32 precision).
// =====================================================================
__global__ __launch_bounds__(64, 2) void proj_mfma_kernel(
    const ushort* __restrict__ WpQ, const ushort* __restrict__ WpK,
    const ushort* __restrict__ Ap, const int* __restrict__ vl,
    float* __restrict__ Eq, ushort* __restrict__ EkTb) {
  const int lane = threadIdx.x;
  const int lr = lane & 15, lg = lane >> 4;
  const int bx = blockIdx.x;
  const int rp = bx >> 2, cg = bx & 3;
  const int r0 = rp * 32;
  const bool isQ = r0 < 1024;
  const ushort* Wp;
  int b = 0, rin = 0;
  if (isQ) {
    Wp = WpQ;
  } else {
    const int rk = r0 - 1024;
    b = rk >> 10; rin = rk & 1023;
    if (rin >= vl[b]) return;
    Wp = WpK;
  }
  const int fb0 = r0 >> 4;  // first of 2 A fragblocks

  __shared__ ushort Wr[2][4][2][512];  // slot, colfrag, half  (16 KB)
  __shared__ ushort Ar[2][2][2][512];  // slot, rowfrag, half  (8 KB)

#define ISSUE(slot, kkv)                                                       \
  {                                                                            \
    _Pragma("unroll") for (int cf = 0; cf < 4; ++cf) {                         \
      _Pragma("unroll") for (int hf = 0; hf < 2; ++hf) {                       \
        const ushort* g = &Wp[(((size_t)(cg * 4 + cf) * 16 + (kkv)) << 10) +   \
                              (hf << 9) + lane * 8];                           \
        __builtin_amdgcn_global_load_lds(                                      \
            (const __attribute__((address_space(1))) void*)g,                  \
            (__attribute__((address_space(3))) void*)&Wr[slot][cf][hf][0],     \
            16, 0, 0);                                                         \
      }                                                                        \
    }                                                                          \
    _Pragma("unroll") for (int rf = 0; rf < 2; ++rf) {                         \
      _Pragma("unroll") for (int hf = 0; hf < 2; ++hf) {                       \
        const ushort* g = &Ap[(((size_t)(fb0 + rf) * 16 + (kkv)) << 10) +      \
                              (hf << 9) + lane * 8];                           \
        __builtin_amdgcn_global_load_lds(                                      \
            (const __attribute__((address_space(1))) void*)g,                  \
            (__attribute__((address_space(3))) void*)&Ar[slot][rf][hf][0],     \
            16, 0, 0);                                                         \
      }                                                                        \
    }                                                                          \
  }

  ISSUE(0, 0);
  ISSUE(1, 1);

  floatx4 acc0[4], acc1[4];
#pragma unroll
  for (int c = 0; c < 4; ++c) {
    acc0[c] = (floatx4){0.f, 0.f, 0.f, 0.f};
    acc1[c] = (floatx4){0.f, 0.f, 0.f, 0.f};
  }

#pragma unroll
  for (int kk = 0; kk < 16; ++kk) {
    const int sl = kk & 1;
    if (kk < 15) asm volatile("s_waitcnt vmcnt(12)" ::: "memory");
    else         asm volatile("s_waitcnt vmcnt(0)" ::: "memory");
    const short8v ah0 = *(const short8v*)&Ar[sl][0][0][lane * 8];
    const short8v al0 = *(const short8v*)&Ar[sl][0][1][lane * 8];
    const short8v ah1 = *(const short8v*)&Ar[sl][1][0][lane * 8];
    const short8v al1 = *(const short8v*)&Ar[sl][1][1][lane * 8];
#pragma unroll
    for (int c = 0; c < 4; ++c) {
      const short8v wh = *(const short8v*)&Wr[sl][c][0][lane * 8];
      const short8v wl = *(const short8v*)&Wr[sl][c][1][lane * 8];
      acc0[c] = __builtin_amdgcn_mfma_f32_16x16x32_bf16(al0, wh, acc0[c], 0, 0, 0);
      acc0[c] = __builtin_amdgcn_mfma_f32_16x16x32_bf16(ah0, wl, acc0[c], 0, 0, 0);
      acc0[c] = __builtin_amdgcn_mfma_f32_16x16x32_bf16(ah0, wh, acc0[c], 0, 0, 0);
      acc1[c] = __builtin_amdgcn_mfma_f32_16x16x32_bf16(al1, wh, acc1[c], 0, 0, 0);
      acc1[c] = __builtin_amdgcn_mfma_f32_16x16x32_bf16(ah1, wl, acc1[c], 0, 0, 0);
      acc1[c] = __builtin_amdgcn_mfma_f32_16x16x32_bf16(ah1, wh, acc1[c], 0, 0, 0);
    }
    if (kk < 14) ISSUE(sl, kk + 2);
  }
#undef ISSUE

  const float C2 = 2.885390081777927f;  // 2*log2(e)
  if (isQ) {
#pragma unroll
    for (int c = 0; c < 4; ++c) {
      const int h = cg * 64 + c * 16 + lr;
#pragma unroll
      for (int reg = 0; reg < 4; ++reg) {
        const int row0 = r0 + lg * 4 + reg;
        float p0 = fminf(fmaxf(acc0[c][reg], -15.f), 15.f);
        float p1 = fminf(fmaxf(acc1[c][reg], -15.f), 15.f);
        Eq[(size_t)row0 * NH + h] = exp2f(p0 * C2);
        Eq[(size_t)(row0 + 16) * NH + h] = exp2f(p1 * C2);
      }
    }
  } else {
#pragma unroll
    for (int c = 0; c < 4; ++c) {
      const int h = cg * 64 + c * 16 + lr;
      ushort4 e0, e1;
      e0.x = f2bf(exp2f(fminf(fmaxf(acc0[c][0], -15.f), 15.f) * C2));
      e0.y = f2bf(exp2f(fminf(fmaxf(acc0[c][1], -15.f), 15.f) * C2));
      e0.z = f2bf(exp2f(fminf(fmaxf(acc0[c][2], -15.f), 15.f) * C2));
      e0.w = f2bf(exp2f(fminf(fmaxf(acc0[c][3], -15.f), 15.f) * C2));
      e1.x = f2bf(exp2f(fminf(fmaxf(acc1[c][0], -15.f), 15.f) * C2));
      e1.y = f2bf(exp2f(fminf(fmaxf(acc1[c][1], -15.f), 15.f) * C2));
      e1.z = f2bf(exp2f(fminf(fmaxf(acc1[c][2], -15.f), 15.f) * C2));
      e1.w = f2bf(exp2f(fminf(fmaxf(acc1[c][3], -15.f), 15.f) * C2));
      *(ushort4*)&EkTb[((size_t)(b * NH + h)) * NK + rin + lg * 4] = e0;
      *(ushort4*)&EkTb[((size_t)(b * NH + h)) * NK + rin + 16 + lg * 4] = e1;
    }
  }
}

// =====================================================================
// K2 v5: scores -> fixed-shift softmax numerators + row sums, 4 q/block.
// p = exp2(-2log2e*(racc+SN)), SN = sum_h max(-wv_h,0)  (exact shift).
// grid (32 q-quads, 4 kt, 8 b), 256 thr; Pb written packed for pv.
// =====================================================================
__global__ __launch_bounds__(256, 2) void score_kernel(
    const float* __restrict__ Eq, const ushort* __restrict__ EkTb,
    const float* __restrict__ wvp, const int* __restrict__ valid_lens,
    ushort* __restrict__ Pbp, float* __restrict__ rowsum) {
  const int b = blockIdx.z;
  const int V = valid_lens[b];
  const int k0 = blockIdx.y * 256;
  if (k0 >= V) return;
  const int t = threadIdx.x;
  const int q0 = blockIdx.x * 4;
  const int lane = t & 63, wid = t >> 6;
  const float L2E2 = 2.8853900817779268f;  // 2*log2(e)

  __shared__ __align__(16) float eqs[4][NH];
  __shared__ __align__(16) float wvs[NH];
  __shared__ float red[20];

  ((float4*)eqs)[t] = ((const float4*)&Eq[(size_t)(b * NQ + q0) * NH])[t];
  wvs[t] = wvp[t];
  __syncthreads();

  float mn = wave_rsum(fminf(wvs[t], 0.f));
  if (lane == 0) red[wid] = mn;
  __syncthreads();
  const float SN = -(red[0] + red[1] + red[2] + red[3]);

  const ushort* ek = EkTb + (size_t)b * NH * NK + k0 + t;
  float a0 = 0.f, a1 = 0.f, a2 = 0.f, a3 = 0.f;

  ushort uA[8], uB[8];
#define LOADE(u, h0)                                                      \
  {                                                                       \
    _Pragma("unroll") for (int j = 0; j < 8; ++j)                         \
        u[j] = ek[(size_t)((h0) + j) * NK];                               \
  }
#define CHUNK(u, h0)                                                      \
  {                                                                       \
    float e0[8], e1[8], e2[8], e3[8], w8[8];                              \
    *(float4*)&e0[0] = *(const float4*)&eqs[0][(h0)];                     \
    *(float4*)&e0[4] = *(const float4*)&eqs[0][(h0) + 4];                 \
    *(float4*)&e1[0] = *(const float4*)&eqs[1][(h0)];                     \
    *(float4*)&e1[4] = *(const float4*)&eqs[1][(h0) + 4];                 \
    *(float4*)&e2[0] = *(const float4*)&eqs[2][(h0)];                     \
    *(float4*)&e2[4] = *(const float4*)&eqs[2][(h0) + 4];                 \
    *(float4*)&e3[0] = *(const float4*)&eqs[3][(h0)];                     \
    *(float4*)&e3[4] = *(const float4*)&eqs[3][(h0) + 4];                 \
    *(float4*)&w8[0] = *(const float4*)&wvs[(h0)];                        \
    *(float4*)&w8[4] = *(const float4*)&wvs[(h0) + 4];                    \
    _Pragma("unroll") for (int j = 0; j < 8; ++j) {                       \
      const float ev = bf2f(u[j]);                                        \
      a0 += w8[j] * __builtin_amdgcn_rcpf(__builtin_fmaf(e0[j], ev, 1.f)); \
      a1 += w8[j] * __builtin_amdgcn_rcpf(__builtin_fmaf(e1[j], ev, 1.f)); \
      a2 += w8[j] * __builtin_amdgcn_rcpf(__builtin_fmaf(e2[j], ev, 1.f)); \
      a3 += w8[j] * __builtin_amdgcn_rcpf(__builtin_fmaf(e3[j], ev, 1.f)); \
    }                                                                     \
  }

  LOADE(uA, 0);
#pragma unroll 1
  for (int h0 = 0; h0 < NH; h0 += 16) {
    LOADE(uB, h0 + 8);
    CHUNK(uA, h0);
    if (h0 + 16 < NH) LOADE(uA, h0 + 16);
    CHUNK(uB, h0 + 8);
  }
#undef LOADE
#undef CHUNK

  const int k = k0 + t;
  const bool ok = (k < V);
  float p[4];
  p[0] = ok ? exp2f(-L2E2 * (a0 + SN)) : 0.f;
  p[1] = ok ? exp2f(-L2E2 * (a1 + SN)) : 0.f;
  p[2] = ok ? exp2f(-L2E2 * (a2 + SN)) : 0.f;
  p[3] = ok ? exp2f(-L2E2 * (a3 + SN)) : 0.f;

  const size_t blk0 = ((size_t)(b * 8 + (q0 >> 4)) * 32 + (k0 >> 5) + (t >> 5)) * 512;
  const int offk = (((t >> 3) & 3) << 7) + (t & 7);
#pragma unroll
  for (int i = 0; i < 4; ++i) {
    const ushort ui = f2bf(p[i]);
    Pbp[blk0 + (((q0 + i) & 15) << 3) + offk] = ui;
    float s = wave_rsum(bf2f(ui));
    if (lane == 0) red[4 + i * 4 + wid] = s;
  }
  __syncthreads();
  if (t < 4)
    atomicAdd(&rowsum[b * NQ + q0 + t],
              red[4 + t * 4] + red[5 + t * 4] + red[6 + t * 4] + red[7 + t * 4]);
}

// =====================================================================
// K3: PV via MFMA on packed operands, depth-4 named-buffer pipeline.
// out[q][v] = (sum_k Pbp[q,k]*Vp[v,k]) / rowsum[q].
// grid (8 qt, 16 vt2, 8 b), 128 thr; pad kk's read zeroed Pb (safe).
// =====================================================================
__global__ __launch_bounds__(128, 2) void pv_mfma_kernel(
    const ushort* __restrict__ Pbp, const ushort* __restrict__ Vp,
    const float* __restrict__ rowsum, const int* __restrict__ valid_lens,
    float* __restrict__ out) {
  const int w = threadIdx.x >> 6;
  const int lane = threadIdx.x & 63;
  const int lr = lane & 15, lg = lane >> 4;
  const int qt = blockIdx.x, vt2 = blockIdx.y, b = blockIdx.z;
  const int V = valid_lens[b];
  const int Kt4 = (((V + 31) >> 5) + 3) & ~3;
  const int vt = vt2 * 2 + w;
  const ushort* pbase = Pbp + ((size_t)(b * 8 + qt) * 32) * 512 + lane * 8;
  const ushort* vbase = Vp + ((size_t)(b * 32 + vt) * 32) * 512 + lane * 8;

#define LP(s) (*(const short8v*)&pbase[(size_t)(s) * 512])
#define LV(s) (*(const short8v*)&vbase[(size_t)(s) * 512])

  floatx4 acc0 = (floatx4){0.f, 0.f, 0.f, 0.f};
  floatx4 acc1 = (floatx4){0.f, 0.f, 0.f, 0.f};
  short8v pA, vA, pB, vB, pC, vC, pD, vD;
  pA = LP(0); vA = LV(0);          // Kt4 >= 4 always
  pB = LP(1); vB = LV(1);
  pC = LP(2); vC = LV(2);
  for (int s = 0; s < Kt4; s += 4) {
    pD = LP(s + 3); vD = LV(s + 3);
    acc0 = __builtin_amdgcn_mfma_f32_16x16x32_bf16(pA, vA, acc0, 0, 0, 0);
    if (s + 4 < Kt4) { pA = LP(s + 4); vA = LV(s + 4); }
    acc1 = __builtin_amdgcn_mfma_f32_16x16x32_bf16(pB, vB, acc1, 0, 0, 0);
    if (s + 5 < Kt4) { pB = LP(s + 5); vB = LV(s + 5); }
    acc0 = __builtin_amdgcn_mfma_f32_16x16x32_bf16(pC, vC, acc0, 0, 0, 0);
    if (s + 6 < Kt4) { pC = LP(s + 6); vC = LV(s + 6); }
    acc1 = __builtin_amdgcn_mfma_f32_16x16x32_bf16(pD, vD, acc1, 0, 0, 0);
  }
#undef LP
#undef LV

#pragma unroll
  for (int reg = 0; reg < 4; ++reg) {
    const int row = b * NQ + qt * 16 + lg * 4 + reg;
    const float rs = __builtin_amdgcn_rcpf(rowsum[row]);
    out[(size_t)row * NV + vt * 16 + lr] = (acc0[reg] + acc1[reg]) * rs;
  }
}

// =====================================================================
extern "C" void kernel_launch(void* const* d_in, const int* in_sizes, int n_in,
                              void* d_out, int out_size, void* d_ws, size_t ws_size,
                              hipStream_t stream) {
  const float* queries = (const float*)d_in[0];
  const float* keys    = (const float*)d_in[1];
  const float* values  = (const float*)d_in[2];
  const int*   vlens   = (const int*)d_in[3];
  const float* Wq      = (const float*)d_in[4];
  const float* Wk      = (const float*)d_in[5];
  const float* wv      = (const float*)d_in[6];
  float* out = (float*)d_out;

  char* base = (char*)d_ws;
  ushort* WpQ  = (ushort*)base;                       // 512KB packed hi/lo
  ushort* WpK  = WpQ + 256 * 1024;                    // 512KB
  float*  Eq   = (float*)(base + (1 << 20));          // 1MB
  ushort* EkTb = (ushort*)(base + (2 << 20));         // 4MB
  ushort* Pbp  = (ushort*)(base + (6 << 20));         // 2MB packed
  ushort* Vp   = (ushort*)(base + (8 << 20));         // 8MB packed
  float*  rowsum = (float*)(base + (16 << 20));       // 4KB
  ushort* Ap   = (ushort*)(base + (17 << 20));        // 18MB packed hi/lo
  // total 35MB

  prep_kernel<<<dim3(6529), dim3(256), 0, stream>>>(
      queries, keys, values, vlens, Wq, Wk, WpQ, WpK, Ap, Vp, rowsum);
  proj_mfma_kernel<<<dim3(1152), dim3(64), 0, stream>>>(
      WpQ, WpK, Ap, vlens, Eq, EkTb);
  score_kernel<<<dim3(32, 4, 8), dim3(256), 0, stream>>>(
      Eq, EkTb, wv, vlens, Pbp, rowsum);
  pv_mfma_kernel<<<dim3(8, 16, 8), dim3(128), 0, stream>>>(
      Pbp, Vp, rowsum, vlens, out);
}